// Round 1
// baseline (326.106 us; speedup 1.0000x reference)
//
#include <hip/hip_runtime.h>
#include <hip/hip_bf16.h>

// Eq2NetSet: x = concat(emb[xcat], xfeat) [B,256,64]; pairwise p_ij = x_i*x_j;
// 3-layer MLP (64->128->128->128) per pair; relu; mean over (i,j); decoder MLP -> [B,1].
// Strategy: triangle i<=j (weight 2 off-diag), lanes=pairs, waves=channel quarters,
// weights via scalar loads (wave-uniform), activations in XOR-swizzled LDS (64KB/block).

#define NB 4
#define NN 256
#define HD 128
#define TILES_PER_B 514   // 32896 pairs / 64 per tile

__global__ void prep_kernel(const int* __restrict__ xcat,
                            const float* __restrict__ xfeat,
                            const float* __restrict__ emb,
                            float* __restrict__ x,
                            float* __restrict__ pooled)
{
    int f = blockIdx.x * 256 + threadIdx.x;      // 65536 threads total
    int d = f & 63;
    int n = (f >> 6) & 255;
    int b = f >> 14;
    int nn = (b << 8) + n;
    float v;
    if (d < 63) v = emb[xcat[nn] * 63 + d];
    else        v = xfeat[nn];
    x[f] = v;
    if (f < NB * HD) pooled[f] = 0.0f;           // zero the pooled accumulator
}

// one layer from LDS row (K=128) -> acc[32], weights via uniform (scalar) loads
__device__ __forceinline__ void layer_from_lds(const float* __restrict__ row, int sw,
                                               const float* __restrict__ W,
                                               const float* __restrict__ bias,
                                               int cbase, float acc[32])
{
#pragma unroll
    for (int c = 0; c < 32; ++c) acc[c] = bias[cbase + c];
    float4 h0 = *(const float4*)(row + ((0 ^ sw) << 2));
    float4 h1 = *(const float4*)(row + ((1 ^ sw) << 2));
    for (int kb = 0; kb < 16; ++kb) {
        float pk[8] = {h0.x, h0.y, h0.z, h0.w, h1.x, h1.y, h1.z, h1.w};
        if (kb < 15) {
            h0 = *(const float4*)(row + (((2 * kb + 2) ^ sw) << 2));
            h1 = *(const float4*)(row + (((2 * kb + 3) ^ sw) << 2));
        }
        const float* wrow = W + (kb << 10) + cbase;   // kb*8 rows * 128
#pragma unroll
        for (int kk = 0; kk < 8; ++kk) {
#pragma unroll
            for (int c = 0; c < 32; ++c)
                acc[c] = fmaf(pk[kk], wrow[(kk << 7) + c], acc[c]);
        }
    }
}

// layer 1: p[d] = xi[d]*xj[d] built on the fly from global x (L1/L2-resident), K=64
__device__ __forceinline__ void layer1(const float4* __restrict__ xi4,
                                       const float4* __restrict__ xj4,
                                       const float* __restrict__ W1,
                                       const float* __restrict__ b1,
                                       int cbase, float acc[32])
{
#pragma unroll
    for (int c = 0; c < 32; ++c) acc[c] = b1[cbase + c];
    float4 a0 = xi4[0], a1 = xi4[1], u0 = xj4[0], u1 = xj4[1];
    for (int kb = 0; kb < 8; ++kb) {
        float pk[8] = {a0.x * u0.x, a0.y * u0.y, a0.z * u0.z, a0.w * u0.w,
                       a1.x * u1.x, a1.y * u1.y, a1.z * u1.z, a1.w * u1.w};
        if (kb < 7) {
            a0 = xi4[2 * kb + 2]; a1 = xi4[2 * kb + 3];
            u0 = xj4[2 * kb + 2]; u1 = xj4[2 * kb + 3];
        }
        const float* wrow = W1 + (kb << 10) + cbase;
#pragma unroll
        for (int kk = 0; kk < 8; ++kk) {
#pragma unroll
            for (int c = 0; c < 32; ++c)
                acc[c] = fmaf(pk[kk], wrow[(kk << 7) + c], acc[c]);
        }
    }
}

__device__ __forceinline__ void store_relu(float* __restrict__ row, int sw, int cbase,
                                           const float acc[32])
{
#pragma unroll
    for (int ch = 0; ch < 8; ++ch) {
        float4 v;
        v.x = fmaxf(acc[4 * ch + 0], 0.0f);
        v.y = fmaxf(acc[4 * ch + 1], 0.0f);
        v.z = fmaxf(acc[4 * ch + 2], 0.0f);
        v.w = fmaxf(acc[4 * ch + 3], 0.0f);
        *(float4*)(row + ((((cbase >> 2) + ch) ^ sw) << 2)) = v;
    }
}

__global__ __launch_bounds__(256, 2) void pair_mlp(
    const float* __restrict__ x,
    const float* __restrict__ W1, const float* __restrict__ b1,
    const float* __restrict__ W2, const float* __restrict__ b2,
    const float* __restrict__ W3, const float* __restrict__ b3,
    float* __restrict__ pooled)
{
    __shared__ float smA[64 * HD];   // 32 KB
    __shared__ float smB[64 * HD];   // 32 KB  (total 64 KB -> 2 blocks/CU)

    const int tid  = threadIdx.x;
    const int lane = tid & 63;                 // lane = pair within tile
    const int cbase = __builtin_amdgcn_readfirstlane((tid >> 6) << 5); // wave's 32-channel base
    const int b = blockIdx.y;
    const float* xb = x + (b << 14);           // b*256*64
    const int sw = lane & 31;                  // LDS XOR swizzle key
    float* rowA = smA + (lane << 7);
    float* rowB = smB + (lane << 7);
    float pool_acc = 0.0f;

    // rotate block index per batch so leftover tiles land on distinct CUs
    const int bx = (blockIdx.x + (blockIdx.y << 6)) & 255;

    for (int tl = bx; tl < TILES_PER_B; tl += 256) {
        const int t = (tl << 6) + lane;        // triangle index, always < 32896
        // t -> (i,j), i<=j:  t = j(j+1)/2 + i
        int j = (int)((sqrtf(8.0f * (float)t + 1.0f) - 1.0f) * 0.5f);
        while (((j + 1) * (j + 2) >> 1) <= t) ++j;
        while (((j * (j + 1)) >> 1) > t) --j;
        const int i = t - ((j * (j + 1)) >> 1);

        const float4* xi4 = (const float4*)(xb + (i << 6));
        const float4* xj4 = (const float4*)(xb + (j << 6));

        float acc[32];
        layer1(xi4, xj4, W1, b1, cbase, acc);
        store_relu(rowA, sw, cbase, acc);
        __syncthreads();

        layer_from_lds(rowA, sw, W2, b2, cbase, acc);
        store_relu(rowB, sw, cbase, acc);
        __syncthreads();

        layer_from_lds(rowB, sw, W3, b3, cbase, acc);

        // relu, pair weight (2x off-diagonal), cross-lane (cross-pair) reduction
        const float wp = (i == j) ? 1.0f : 2.0f;
#pragma unroll
        for (int c = 0; c < 32; ++c) {
            float v = fmaxf(acc[c], 0.0f) * wp;
            v += __shfl_xor(v, 1, 64);
            v += __shfl_xor(v, 2, 64);
            v += __shfl_xor(v, 4, 64);
            v += __shfl_xor(v, 8, 64);
            v += __shfl_xor(v, 16, 64);
            v += __shfl_xor(v, 32, 64);
            pool_acc += (lane == c) ? v : 0.0f;  // lane c keeps channel cbase+c
        }
    }

    if (lane < 32)
        atomicAdd(pooled + (b << 7) + cbase + lane, pool_acc);
}

__global__ void decoder_kernel(const float* __restrict__ pooled,
                               const float* __restrict__ D1, const float* __restrict__ c1,
                               const float* __restrict__ D2, const float* __restrict__ c2,
                               const float* __restrict__ D3, const float* __restrict__ c3,
                               float* __restrict__ out)
{
    __shared__ float hb[HD];
    __shared__ float tb[HD];
    const int b = blockIdx.x;
    const int t = threadIdx.x;   // 128 threads

    hb[t] = fmaxf(pooled[(b << 7) + t] * (1.0f / 65536.0f), 0.0f);
    __syncthreads();

    float a = c1[t];
    for (int k = 0; k < HD; ++k) a = fmaf(hb[k], D1[(k << 7) + t], a);
    tb[t] = fmaxf(a, 0.0f);
    __syncthreads();

    a = c2[t];
    for (int k = 0; k < HD; ++k) a = fmaf(tb[k], D2[(k << 7) + t], a);
    __syncthreads();             // all reads of hb done before overwrite
    hb[t] = fmaxf(a, 0.0f);
    __syncthreads();

    if (t == 0) {
        float s = c3[0];
        for (int k = 0; k < HD; ++k) s = fmaf(hb[k], D3[k], s);
        out[b] = s;
    }
}

extern "C" void kernel_launch(void* const* d_in, const int* in_sizes, int n_in,
                              void* d_out, int out_size, void* d_ws, size_t ws_size,
                              hipStream_t stream)
{
    (void)in_sizes; (void)n_in; (void)out_size; (void)ws_size;

    const int*   xcat  = (const int*)  d_in[0];
    const float* xfeat = (const float*)d_in[1];
    const float* emb   = (const float*)d_in[2];
    const float* W1    = (const float*)d_in[3];
    const float* b1    = (const float*)d_in[4];
    const float* W2    = (const float*)d_in[5];
    const float* b2    = (const float*)d_in[6];
    const float* W3    = (const float*)d_in[7];
    const float* b3    = (const float*)d_in[8];
    const float* D1    = (const float*)d_in[9];
    const float* c1    = (const float*)d_in[10];
    const float* D2    = (const float*)d_in[11];
    const float* c2    = (const float*)d_in[12];
    const float* D3    = (const float*)d_in[13];
    const float* c3    = (const float*)d_in[14];
    float* out = (float*)d_out;

    float* x      = (float*)d_ws;          // 65536 floats
    float* pooled = x + NB * NN * 64;      // 512 floats

    prep_kernel<<<256, 256, 0, stream>>>(xcat, xfeat, emb, x, pooled);
    pair_mlp<<<dim3(256, NB), 256, 0, stream>>>(x, W1, b1, W2, b2, W3, b3, pooled);
    decoder_kernel<<<NB, HD, 0, stream>>>(pooled, D1, c1, D2, c2, D3, c3, out);
}

// Round 2
// 202.495 us; speedup vs baseline: 1.6104x; 1.6104x over previous
//
#include <hip/hip_runtime.h>
#include <hip/hip_bf16.h>

// Eq2NetSet via bf16 MFMA (16x16x32, fp32 accum).
// Orientation: channels = M, pairs = N.  Per block: 128 triangle pairs.
//   L1: H1^T[c][p] = W1^T (A) @ P^T (B),  K=64
//   L2: H2^T = W2^T @ H1^T,               K=128
//   L3: H3^T = W3^T @ H2^T,               K=128 -> relu -> weighted pair-sum -> atomicAdd pooled
// A-frags (weights) pre-packed fragment-linear in ws (one 16B coalesced load each).
// B-frags (activations) from LDS rows [pair][ch] bf16 with XOR-16B-chunk swizzle keyed on pair.
// C/D: col=lane&15 (pair), row=(lane>>4)*4+r (channel) -> 4 consecutive channels/lane -> ds_write_b64.
// Triangle i<=j, weight 2 off-diagonal; 32896 pairs/batch = 257 tiles * 128 exactly.

#define NB 4
#define NN 256
#define HD 128

typedef __attribute__((ext_vector_type(8))) short bf16x8;
typedef __attribute__((ext_vector_type(4))) short short4v;
typedef __attribute__((ext_vector_type(4))) float f32x4;

__device__ __forceinline__ short f2bf(float f) {
    // bf16 round-to-nearest-even (finite inputs)
    unsigned u = __builtin_bit_cast(unsigned, f);
    u = (u + 0x7fff + ((u >> 16) & 1)) >> 16;
    return (short)u;
}

__device__ __forceinline__ void tri_ij(int t, int& i, int& j) {
    j = (int)((sqrtf(8.0f * (float)t + 1.0f) - 1.0f) * 0.5f);
    while (((j + 1) * (j + 2) >> 1) <= t) ++j;
    while (((j * (j + 1)) >> 1) > t) --j;
    i = t - ((j * (j + 1)) >> 1);
}

// pack W[fanin][128] into A-fragment-linear bf16: packed[(mt*KQ+kq)*64 + lane][j],
// value = W[kq*32 + (lane>>4)*8 + j][mt*16 + (lane&15)]
__device__ __forceinline__ void pack_w(const float* __restrict__ W, short* __restrict__ pw,
                                       int KQ, int u) {
    int l  = u & 63;
    int kq = (u >> 6) % KQ;
    int mt = (u >> 6) / KQ;
    int q = l >> 4, m = l & 15;
    int c = mt * 16 + m;
#pragma unroll
    for (int j = 0; j < 8; ++j) {
        int k = kq * 32 + q * 8 + j;
        pw[u * 8 + j] = f2bf(W[k * 128 + c]);
    }
}

__global__ void prep_kernel(const int* __restrict__ xcat,
                            const float* __restrict__ xfeat,
                            const float* __restrict__ emb,
                            const float* __restrict__ W1,
                            const float* __restrict__ W2,
                            const float* __restrict__ W3,
                            float* __restrict__ x,
                            float* __restrict__ pooled,
                            short* __restrict__ pw1,
                            short* __restrict__ pw2,
                            short* __restrict__ pw3)
{
    int bid = blockIdx.x;
    int tid = threadIdx.x;
    if (bid < 256) {                       // build x[4][256][64] fp32 + zero pooled
        int f = bid * 256 + tid;
        int d = f & 63;
        int nn = f >> 6;                   // b*256+n
        float v;
        if (d < 63) v = emb[xcat[nn] * 63 + d];
        else        v = xfeat[nn];
        x[f] = v;
        if (f < NB * HD) pooled[f] = 0.0f;
    } else if (bid < 260) {                // W1: 8mt*2kq*64 = 1024 threads
        pack_w(W1, pw1, 2, (bid - 256) * 256 + tid);
    } else if (bid < 268) {                // W2: 8mt*4kq*64 = 2048
        pack_w(W2, pw2, 4, (bid - 260) * 256 + tid);
    } else {                               // W3
        pack_w(W3, pw3, 4, (bid - 268) * 256 + tid);
    }
}

__global__ __launch_bounds__(256, 3) void pair_mlp(
    const float* __restrict__ x,
    const short* __restrict__ pw1, const float* __restrict__ b1,
    const short* __restrict__ pw2, const float* __restrict__ b2,
    const short* __restrict__ pw3, const float* __restrict__ b3,
    float* __restrict__ pooled)
{
    __shared__ short smP[128 * 64];    // 16 KB  P^T tile, row=pair, 64 bf16 (8 chunks)
    __shared__ short smH[128 * 128];   // 32 KB  H tile,   row=pair, 128 bf16 (16 chunks)

    const int tid = threadIdx.x;
    const int l = tid & 63;
    const int w = __builtin_amdgcn_readfirstlane(tid >> 6);  // wave 0..3
    const int wm = w >> 1;             // channel half: mt in [wm*4, wm*4+4)
    const int wn = w & 1;              // pair half:    pairs [wn*64, wn*64+64)
    const int q = l >> 4;
    const int m = l & 15;
    const int b = blockIdx.y;
    const int tbase = blockIdx.x * 128;          // triangle index base for this tile
    const float* xb = x + (b << 14);
    char* smPc = (char*)smP;
    char* smHc = (char*)smH;

    // ---- build P^T tile: 256 threads, thread = (pair p = tid>>1, half = tid&1) ----
    {
        const int p = tid >> 1;
        const int half = tid & 1;
        int i, j;
        tri_ij(tbase + p, i, j);
        const float4* xi4 = (const float4*)(xb + (i << 6) + half * 32);
        const float4* xj4 = (const float4*)(xb + (j << 6) + half * 32);
#pragma unroll
        for (int c = 0; c < 4; ++c) {
            float4 a0 = xi4[2 * c], a1 = xi4[2 * c + 1];
            float4 u0 = xj4[2 * c], u1 = xj4[2 * c + 1];
            bf16x8 s;
            s[0] = f2bf(a0.x * u0.x); s[1] = f2bf(a0.y * u0.y);
            s[2] = f2bf(a0.z * u0.z); s[3] = f2bf(a0.w * u0.w);
            s[4] = f2bf(a1.x * u1.x); s[5] = f2bf(a1.y * u1.y);
            s[6] = f2bf(a1.z * u1.z); s[7] = f2bf(a1.w * u1.w);
            int chunk = half * 4 + c;
            int phys = chunk ^ (p & 7);
            *(bf16x8*)(smPc + p * 128 + phys * 16) = s;
        }
    }
    __syncthreads();

    f32x4 acc[4][4];
    const f32x4 zero = {0.f, 0.f, 0.f, 0.f};

    // ---- L1: K=64, B from smP ----
#pragma unroll
    for (int mt = 0; mt < 4; ++mt)
#pragma unroll
        for (int nt = 0; nt < 4; ++nt) acc[mt][nt] = zero;

#pragma unroll
    for (int kq = 0; kq < 2; ++kq) {
        bf16x8 bfr[4], afr[4];
#pragma unroll
        for (int nt = 0; nt < 4; ++nt) {
            int pair = wn * 64 + nt * 16 + m;
            int phys = (kq * 4 + q) ^ (pair & 7);
            bfr[nt] = *(const bf16x8*)(smPc + pair * 128 + phys * 16);
        }
#pragma unroll
        for (int mt = 0; mt < 4; ++mt)
            afr[mt] = *(const bf16x8*)(pw1 + ((((wm * 4 + mt) * 2 + kq) * 64 + l) << 3));
#pragma unroll
        for (int mt = 0; mt < 4; ++mt)
#pragma unroll
            for (int nt = 0; nt < 4; ++nt)
                acc[mt][nt] = __builtin_amdgcn_mfma_f32_16x16x32_bf16(afr[mt], bfr[nt], acc[mt][nt], 0, 0, 0);
    }

    // epilogue L1 -> smH (bias + relu + bf16), swizzled ds_write_b64
#pragma unroll
    for (int mt = 0; mt < 4; ++mt) {
        int mtg = wm * 4 + mt;
        float4 bv = *(const float4*)(b1 + mtg * 16 + q * 4);
#pragma unroll
        for (int nt = 0; nt < 4; ++nt) {
            int pair = wn * 64 + nt * 16 + m;
            short4v sv;
            sv[0] = f2bf(fmaxf(acc[mt][nt][0] + bv.x, 0.f));
            sv[1] = f2bf(fmaxf(acc[mt][nt][1] + bv.y, 0.f));
            sv[2] = f2bf(fmaxf(acc[mt][nt][2] + bv.z, 0.f));
            sv[3] = f2bf(fmaxf(acc[mt][nt][3] + bv.w, 0.f));
            int chunk = mtg * 2 + (q >> 1);
            int phys = chunk ^ (pair & 15);
            *(short4v*)(smHc + pair * 256 + phys * 16 + (q & 1) * 8) = sv;
        }
    }
    __syncthreads();

    // ---- L2: K=128, B from smH (H1) ----
#pragma unroll
    for (int mt = 0; mt < 4; ++mt)
#pragma unroll
        for (int nt = 0; nt < 4; ++nt) acc[mt][nt] = zero;

#pragma unroll
    for (int kq = 0; kq < 4; ++kq) {
        bf16x8 bfr[4], afr[4];
#pragma unroll
        for (int nt = 0; nt < 4; ++nt) {
            int pair = wn * 64 + nt * 16 + m;
            int phys = (kq * 4 + q) ^ (pair & 15);
            bfr[nt] = *(const bf16x8*)(smHc + pair * 256 + phys * 16);
        }
#pragma unroll
        for (int mt = 0; mt < 4; ++mt)
            afr[mt] = *(const bf16x8*)(pw2 + ((((wm * 4 + mt) * 4 + kq) * 64 + l) << 3));
#pragma unroll
        for (int mt = 0; mt < 4; ++mt)
#pragma unroll
            for (int nt = 0; nt < 4; ++nt)
                acc[mt][nt] = __builtin_amdgcn_mfma_f32_16x16x32_bf16(afr[mt], bfr[nt], acc[mt][nt], 0, 0, 0);
    }
    __syncthreads();   // all reads of H1 done before overwriting smH

    // epilogue L2 -> smH (H2)
#pragma unroll
    for (int mt = 0; mt < 4; ++mt) {
        int mtg = wm * 4 + mt;
        float4 bv = *(const float4*)(b2 + mtg * 16 + q * 4);
#pragma unroll
        for (int nt = 0; nt < 4; ++nt) {
            int pair = wn * 64 + nt * 16 + m;
            short4v sv;
            sv[0] = f2bf(fmaxf(acc[mt][nt][0] + bv.x, 0.f));
            sv[1] = f2bf(fmaxf(acc[mt][nt][1] + bv.y, 0.f));
            sv[2] = f2bf(fmaxf(acc[mt][nt][2] + bv.z, 0.f));
            sv[3] = f2bf(fmaxf(acc[mt][nt][3] + bv.w, 0.f));
            int chunk = mtg * 2 + (q >> 1);
            int phys = chunk ^ (pair & 15);
            *(short4v*)(smHc + pair * 256 + phys * 16 + (q & 1) * 8) = sv;
        }
    }
    __syncthreads();

    // ---- L3: K=128, B from smH (H2) ----
#pragma unroll
    for (int mt = 0; mt < 4; ++mt)
#pragma unroll
        for (int nt = 0; nt < 4; ++nt) acc[mt][nt] = zero;

#pragma unroll
    for (int kq = 0; kq < 4; ++kq) {
        bf16x8 bfr[4], afr[4];
#pragma unroll
        for (int nt = 0; nt < 4; ++nt) {
            int pair = wn * 64 + nt * 16 + m;
            int phys = (kq * 4 + q) ^ (pair & 15);
            bfr[nt] = *(const bf16x8*)(smHc + pair * 256 + phys * 16);
        }
#pragma unroll
        for (int mt = 0; mt < 4; ++mt)
            afr[mt] = *(const bf16x8*)(pw3 + ((((wm * 4 + mt) * 4 + kq) * 64 + l) << 3));
#pragma unroll
        for (int mt = 0; mt < 4; ++mt)
#pragma unroll
            for (int nt = 0; nt < 4; ++nt)
                acc[mt][nt] = __builtin_amdgcn_mfma_f32_16x16x32_bf16(afr[mt], bfr[nt], acc[mt][nt], 0, 0, 0);
    }

    // ---- reduction: relu(h3 + b3) * pair-weight, sum over pairs, atomic to pooled ----
    float wpv[4];
#pragma unroll
    for (int nt = 0; nt < 4; ++nt) {
        int i, j;
        tri_ij(tbase + wn * 64 + nt * 16 + m, i, j);
        wpv[nt] = (i == j) ? 1.0f : 2.0f;
    }
#pragma unroll
    for (int mt = 0; mt < 4; ++mt) {
        int mtg = wm * 4 + mt;
        float4 bv = *(const float4*)(b3 + mtg * 16 + q * 4);
        float vs0 = 0.f, vs1 = 0.f, vs2 = 0.f, vs3 = 0.f;
#pragma unroll
        for (int nt = 0; nt < 4; ++nt) {
            vs0 += wpv[nt] * fmaxf(acc[mt][nt][0] + bv.x, 0.f);
            vs1 += wpv[nt] * fmaxf(acc[mt][nt][1] + bv.y, 0.f);
            vs2 += wpv[nt] * fmaxf(acc[mt][nt][2] + bv.z, 0.f);
            vs3 += wpv[nt] * fmaxf(acc[mt][nt][3] + bv.w, 0.f);
        }
#pragma unroll
        for (int s = 1; s < 16; s <<= 1) {
            vs0 += __shfl_xor(vs0, s, 64);
            vs1 += __shfl_xor(vs1, s, 64);
            vs2 += __shfl_xor(vs2, s, 64);
            vs3 += __shfl_xor(vs3, s, 64);
        }
        if (m == 0) {
            float* pb = pooled + (b << 7) + mtg * 16 + q * 4;
            atomicAdd(pb + 0, vs0);
            atomicAdd(pb + 1, vs1);
            atomicAdd(pb + 2, vs2);
            atomicAdd(pb + 3, vs3);
        }
    }
}

__global__ void decoder_kernel(const float* __restrict__ pooled,
                               const float* __restrict__ D1, const float* __restrict__ c1,
                               const float* __restrict__ D2, const float* __restrict__ c2,
                               const float* __restrict__ D3, const float* __restrict__ c3,
                               float* __restrict__ out)
{
    __shared__ float hb[HD];
    __shared__ float tb[HD];
    const int b = blockIdx.x;
    const int t = threadIdx.x;   // 128 threads

    hb[t] = fmaxf(pooled[(b << 7) + t] * (1.0f / 65536.0f), 0.0f);
    __syncthreads();

    float a = c1[t];
    for (int k = 0; k < HD; ++k) a = fmaf(hb[k], D1[(k << 7) + t], a);
    tb[t] = fmaxf(a, 0.0f);
    __syncthreads();

    a = c2[t];
    for (int k = 0; k < HD; ++k) a = fmaf(tb[k], D2[(k << 7) + t], a);
    __syncthreads();
    hb[t] = fmaxf(a, 0.0f);
    __syncthreads();

    if (t == 0) {
        float s = c3[0];
        for (int k = 0; k < HD; ++k) s = fmaf(hb[k], D3[k], s);
        out[b] = s;
    }
}

extern "C" void kernel_launch(void* const* d_in, const int* in_sizes, int n_in,
                              void* d_out, int out_size, void* d_ws, size_t ws_size,
                              hipStream_t stream)
{
    (void)in_sizes; (void)n_in; (void)out_size; (void)ws_size;

    const int*   xcat  = (const int*)  d_in[0];
    const float* xfeat = (const float*)d_in[1];
    const float* emb   = (const float*)d_in[2];
    const float* W1    = (const float*)d_in[3];
    const float* b1    = (const float*)d_in[4];
    const float* W2    = (const float*)d_in[5];
    const float* b2    = (const float*)d_in[6];
    const float* W3    = (const float*)d_in[7];
    const float* b3    = (const float*)d_in[8];
    const float* D1    = (const float*)d_in[9];
    const float* c1    = (const float*)d_in[10];
    const float* D2    = (const float*)d_in[11];
    const float* c2    = (const float*)d_in[12];
    const float* D3    = (const float*)d_in[13];
    const float* c3    = (const float*)d_in[14];
    float* out = (float*)d_out;

    float* x      = (float*)d_ws;                  // 65536 floats
    float* pooled = x + NB * NN * 64;              // 512 floats
    short* pw1 = (short*)(pooled + NB * HD);       // 8192 shorts (16 KB)
    short* pw2 = pw1 + 8 * 2 * 64 * 8;             // 16384 shorts
    short* pw3 = pw2 + 8 * 4 * 64 * 8;             // 16384 shorts  (total ws ~338 KB)

    prep_kernel<<<276, 256, 0, stream>>>(xcat, xfeat, emb, W1, W2, W3,
                                         x, pooled, pw1, pw2, pw3);
    pair_mlp<<<dim3(257, NB), 256, 0, stream>>>(x, pw1, b1, pw2, b2, pw3, b3, pooled);
    decoder_kernel<<<NB, HD, 0, stream>>>(pooled, D1, c1, D2, c2, D3, c3, out);
}

// Round 3
// 155.949 us; speedup vs baseline: 2.0911x; 1.2985x over previous
//
#include <hip/hip_runtime.h>
#include <hip/hip_bf16.h>

// Eq2NetSet via bf16 MFMA (16x16x32, fp32 accum).
// Orientation: channels = M, pairs = N.  Per block: 128 triangle pairs.
//   L1: H1^T = W1^T (A) @ P^T (B),  K=64
//   L2: H2^T = W2^T @ H1^T,         K=128
//   L3: H3^T = W3^T @ H2^T,         K=128 -> relu -> weighted pair-sum
// Block partials written non-atomically to ws (contended atomicAdd on 512 floats
// was the R2 bottleneck: 263K memory-side atomics on 16 lines = 111 us of chain).
// Fused reduce+decoder kernel finishes the job.

#define NB 4
#define NN 256
#define HD 128

typedef __attribute__((ext_vector_type(8))) short bf16x8;
typedef __attribute__((ext_vector_type(4))) short short4v;
typedef __attribute__((ext_vector_type(4))) float f32x4;

__device__ __forceinline__ short f2bf(float f) {
    // bf16 round-to-nearest-even (finite inputs)
    unsigned u = __builtin_bit_cast(unsigned, f);
    u = (u + 0x7fff + ((u >> 16) & 1)) >> 16;
    return (short)u;
}

__device__ __forceinline__ void tri_ij(int t, int& i, int& j) {
    j = (int)((sqrtf(8.0f * (float)t + 1.0f) - 1.0f) * 0.5f);
    while (((j + 1) * (j + 2) >> 1) <= t) ++j;
    while (((j * (j + 1)) >> 1) > t) --j;
    i = t - ((j * (j + 1)) >> 1);
}

// pack W[fanin][128] into A-fragment-linear bf16: packed[(mt*KQ+kq)*64 + lane][j],
// value = W[kq*32 + (lane>>4)*8 + j][mt*16 + (lane&15)]
__device__ __forceinline__ void pack_w(const float* __restrict__ W, short* __restrict__ pw,
                                       int KQ, int u) {
    int l  = u & 63;
    int kq = (u >> 6) % KQ;
    int mt = (u >> 6) / KQ;
    int q = l >> 4, m = l & 15;
    int c = mt * 16 + m;
#pragma unroll
    for (int j = 0; j < 8; ++j) {
        int k = kq * 32 + q * 8 + j;
        pw[u * 8 + j] = f2bf(W[k * 128 + c]);
    }
}

__global__ void prep_kernel(const int* __restrict__ xcat,
                            const float* __restrict__ xfeat,
                            const float* __restrict__ emb,
                            const float* __restrict__ W1,
                            const float* __restrict__ W2,
                            const float* __restrict__ W3,
                            float* __restrict__ x,
                            short* __restrict__ pw1,
                            short* __restrict__ pw2,
                            short* __restrict__ pw3)
{
    int bid = blockIdx.x;
    int tid = threadIdx.x;
    if (bid < 256) {                       // build x[4][256][64] fp32
        int f = bid * 256 + tid;
        int d = f & 63;
        int nn = f >> 6;                   // b*256+n
        float v;
        if (d < 63) v = emb[xcat[nn] * 63 + d];
        else        v = xfeat[nn];
        x[f] = v;
    } else if (bid < 260) {                // W1: 8mt*2kq*64 = 1024 threads
        pack_w(W1, pw1, 2, (bid - 256) * 256 + tid);
    } else if (bid < 268) {                // W2: 8mt*4kq*64 = 2048
        pack_w(W2, pw2, 4, (bid - 260) * 256 + tid);
    } else {                               // W3
        pack_w(W3, pw3, 4, (bid - 268) * 256 + tid);
    }
}

__global__ __launch_bounds__(256, 3) void pair_mlp(
    const float* __restrict__ x,
    const short* __restrict__ pw1, const float* __restrict__ b1,
    const short* __restrict__ pw2, const float* __restrict__ b2,
    const short* __restrict__ pw3, const float* __restrict__ b3,
    float* __restrict__ partialOut)
{
    __shared__ short smP[128 * 64];    // 16 KB  P^T tile, row=pair, 64 bf16 (8 chunks)
    __shared__ short smH[128 * 128];   // 32 KB  H tile,   row=pair, 128 bf16 (16 chunks)
    __shared__ float smW[128];         // pair weights (1 diag / 2 off-diag)

    const int tid = threadIdx.x;
    const int l = tid & 63;
    const int w = __builtin_amdgcn_readfirstlane(tid >> 6);  // wave 0..3
    const int wm = w >> 1;             // channel half: mt in [wm*4, wm*4+4)
    const int wn = w & 1;              // pair half:    pairs [wn*64, wn*64+64)
    const int q = l >> 4;
    const int m = l & 15;
    const int b = blockIdx.y;
    const int tbase = blockIdx.x * 128;          // triangle index base for this tile
    const float* xb = x + (b << 14);
    char* smPc = (char*)smP;
    char* smHc = (char*)smH;

    // ---- build P^T tile: 256 threads, thread = (pair p = tid>>1, half = tid&1) ----
    {
        const int p = tid >> 1;
        const int half = tid & 1;
        int i, j;
        tri_ij(tbase + p, i, j);
        if (half == 0) smW[p] = (i == j) ? 1.0f : 2.0f;
        const float4* xi4 = (const float4*)(xb + (i << 6) + half * 32);
        const float4* xj4 = (const float4*)(xb + (j << 6) + half * 32);
#pragma unroll
        for (int c = 0; c < 4; ++c) {
            float4 a0 = xi4[2 * c], a1 = xi4[2 * c + 1];
            float4 u0 = xj4[2 * c], u1 = xj4[2 * c + 1];
            bf16x8 s;
            s[0] = f2bf(a0.x * u0.x); s[1] = f2bf(a0.y * u0.y);
            s[2] = f2bf(a0.z * u0.z); s[3] = f2bf(a0.w * u0.w);
            s[4] = f2bf(a1.x * u1.x); s[5] = f2bf(a1.y * u1.y);
            s[6] = f2bf(a1.z * u1.z); s[7] = f2bf(a1.w * u1.w);
            int chunk = half * 4 + c;
            int phys = chunk ^ (p & 7);
            *(bf16x8*)(smPc + p * 128 + phys * 16) = s;
        }
    }
    __syncthreads();

    f32x4 acc[4][4];
    const f32x4 zero = {0.f, 0.f, 0.f, 0.f};

    // ---- L1: K=64, B from smP ----
#pragma unroll
    for (int mt = 0; mt < 4; ++mt)
#pragma unroll
        for (int nt = 0; nt < 4; ++nt) acc[mt][nt] = zero;

#pragma unroll
    for (int kq = 0; kq < 2; ++kq) {
        bf16x8 bfr[4], afr[4];
#pragma unroll
        for (int nt = 0; nt < 4; ++nt) {
            int pair = wn * 64 + nt * 16 + m;
            int phys = (kq * 4 + q) ^ (pair & 7);
            bfr[nt] = *(const bf16x8*)(smPc + pair * 128 + phys * 16);
        }
#pragma unroll
        for (int mt = 0; mt < 4; ++mt)
            afr[mt] = *(const bf16x8*)(pw1 + ((((wm * 4 + mt) * 2 + kq) * 64 + l) << 3));
#pragma unroll
        for (int mt = 0; mt < 4; ++mt)
#pragma unroll
            for (int nt = 0; nt < 4; ++nt)
                acc[mt][nt] = __builtin_amdgcn_mfma_f32_16x16x32_bf16(afr[mt], bfr[nt], acc[mt][nt], 0, 0, 0);
    }

    // epilogue L1 -> smH (bias + relu + bf16), swizzled ds_write_b64
#pragma unroll
    for (int mt = 0; mt < 4; ++mt) {
        int mtg = wm * 4 + mt;
        float4 bv = *(const float4*)(b1 + mtg * 16 + q * 4);
#pragma unroll
        for (int nt = 0; nt < 4; ++nt) {
            int pair = wn * 64 + nt * 16 + m;
            short4v sv;
            sv[0] = f2bf(fmaxf(acc[mt][nt][0] + bv.x, 0.f));
            sv[1] = f2bf(fmaxf(acc[mt][nt][1] + bv.y, 0.f));
            sv[2] = f2bf(fmaxf(acc[mt][nt][2] + bv.z, 0.f));
            sv[3] = f2bf(fmaxf(acc[mt][nt][3] + bv.w, 0.f));
            int chunk = mtg * 2 + (q >> 1);
            int phys = chunk ^ (pair & 15);
            *(short4v*)(smHc + pair * 256 + phys * 16 + (q & 1) * 8) = sv;
        }
    }
    __syncthreads();

    // ---- L2: K=128, B from smH (H1) ----
#pragma unroll
    for (int mt = 0; mt < 4; ++mt)
#pragma unroll
        for (int nt = 0; nt < 4; ++nt) acc[mt][nt] = zero;

#pragma unroll
    for (int kq = 0; kq < 4; ++kq) {
        bf16x8 bfr[4], afr[4];
#pragma unroll
        for (int nt = 0; nt < 4; ++nt) {
            int pair = wn * 64 + nt * 16 + m;
            int phys = (kq * 4 + q) ^ (pair & 15);
            bfr[nt] = *(const bf16x8*)(smHc + pair * 256 + phys * 16);
        }
#pragma unroll
        for (int mt = 0; mt < 4; ++mt)
            afr[mt] = *(const bf16x8*)(pw2 + ((((wm * 4 + mt) * 4 + kq) * 64 + l) << 3));
#pragma unroll
        for (int mt = 0; mt < 4; ++mt)
#pragma unroll
            for (int nt = 0; nt < 4; ++nt)
                acc[mt][nt] = __builtin_amdgcn_mfma_f32_16x16x32_bf16(afr[mt], bfr[nt], acc[mt][nt], 0, 0, 0);
    }
    __syncthreads();   // all reads of H1 done before overwriting smH

    // epilogue L2 -> smH (H2)
#pragma unroll
    for (int mt = 0; mt < 4; ++mt) {
        int mtg = wm * 4 + mt;
        float4 bv = *(const float4*)(b2 + mtg * 16 + q * 4);
#pragma unroll
        for (int nt = 0; nt < 4; ++nt) {
            int pair = wn * 64 + nt * 16 + m;
            short4v sv;
            sv[0] = f2bf(fmaxf(acc[mt][nt][0] + bv.x, 0.f));
            sv[1] = f2bf(fmaxf(acc[mt][nt][1] + bv.y, 0.f));
            sv[2] = f2bf(fmaxf(acc[mt][nt][2] + bv.z, 0.f));
            sv[3] = f2bf(fmaxf(acc[mt][nt][3] + bv.w, 0.f));
            int chunk = mtg * 2 + (q >> 1);
            int phys = chunk ^ (pair & 15);
            *(short4v*)(smHc + pair * 256 + phys * 16 + (q & 1) * 8) = sv;
        }
    }
    __syncthreads();

    // ---- L3: K=128, B from smH (H2) ----
#pragma unroll
    for (int mt = 0; mt < 4; ++mt)
#pragma unroll
        for (int nt = 0; nt < 4; ++nt) acc[mt][nt] = zero;

#pragma unroll
    for (int kq = 0; kq < 4; ++kq) {
        bf16x8 bfr[4], afr[4];
#pragma unroll
        for (int nt = 0; nt < 4; ++nt) {
            int pair = wn * 64 + nt * 16 + m;
            int phys = (kq * 4 + q) ^ (pair & 15);
            bfr[nt] = *(const bf16x8*)(smHc + pair * 256 + phys * 16);
        }
#pragma unroll
        for (int mt = 0; mt < 4; ++mt)
            afr[mt] = *(const bf16x8*)(pw3 + ((((wm * 4 + mt) * 4 + kq) * 64 + l) << 3));
#pragma unroll
        for (int mt = 0; mt < 4; ++mt)
#pragma unroll
            for (int nt = 0; nt < 4; ++nt)
                acc[mt][nt] = __builtin_amdgcn_mfma_f32_16x16x32_bf16(afr[mt], bfr[nt], acc[mt][nt], 0, 0, 0);
    }

    // ---- reduction: relu(h3 + b3) * pair-weight, sum over pairs -> LDS -> ws ----
    float wpv[4];
#pragma unroll
    for (int nt = 0; nt < 4; ++nt)
        wpv[nt] = smW[wn * 64 + nt * 16 + m];

    float* smPart = (float*)smP;   // 256 floats; smP dead since L1
#pragma unroll
    for (int mt = 0; mt < 4; ++mt) {
        int mtg = wm * 4 + mt;
        float4 bv = *(const float4*)(b3 + mtg * 16 + q * 4);
        float vs0 = 0.f, vs1 = 0.f, vs2 = 0.f, vs3 = 0.f;
#pragma unroll
        for (int nt = 0; nt < 4; ++nt) {
            vs0 += wpv[nt] * fmaxf(acc[mt][nt][0] + bv.x, 0.f);
            vs1 += wpv[nt] * fmaxf(acc[mt][nt][1] + bv.y, 0.f);
            vs2 += wpv[nt] * fmaxf(acc[mt][nt][2] + bv.z, 0.f);
            vs3 += wpv[nt] * fmaxf(acc[mt][nt][3] + bv.w, 0.f);
        }
#pragma unroll
        for (int s = 1; s < 16; s <<= 1) {
            vs0 += __shfl_xor(vs0, s, 64);
            vs1 += __shfl_xor(vs1, s, 64);
            vs2 += __shfl_xor(vs2, s, 64);
            vs3 += __shfl_xor(vs3, s, 64);
        }
        if (m == 0) {
            float* p = smPart + wn * HD + mtg * 16 + q * 4;
            p[0] = vs0; p[1] = vs1; p[2] = vs2; p[3] = vs3;
        }
    }
    __syncthreads();

    if (tid < HD) {
        float v = smPart[tid] + smPart[HD + tid];
        partialOut[(b * 257 + blockIdx.x) * HD + tid] = v;   // coalesced 512B/block
    }
}

__global__ void reduce_decode(const float* __restrict__ partial,
                              const float* __restrict__ D1, const float* __restrict__ c1,
                              const float* __restrict__ D2, const float* __restrict__ c2,
                              const float* __restrict__ D3, const float* __restrict__ c3,
                              float* __restrict__ out)
{
    __shared__ float red[2][HD];
    __shared__ float hb[HD];
    __shared__ float tb[HD];
    const int b = blockIdx.x;
    const int t = threadIdx.x;          // 256 threads
    const int ch = t & 127, hf = t >> 7;

    // sum 257 tile-partials per channel (split over 2 halves)
    float s = 0.f;
    for (int tl = hf; tl < 257; tl += 2)
        s += partial[(b * 257 + tl) * HD + ch];
    red[hf][ch] = s;
    __syncthreads();
    if (hf == 0)
        hb[ch] = fmaxf((red[0][ch] + red[1][ch]) * (1.0f / 65536.0f), 0.0f);
    __syncthreads();

    // dec layer 1 (split-k)
    float a = 0.f;
    for (int k = hf * 64; k < hf * 64 + 64; ++k)
        a = fmaf(hb[k], D1[(k << 7) + ch], a);
    red[hf][ch] = a;
    __syncthreads();
    if (hf == 0)
        tb[ch] = fmaxf(red[0][ch] + red[1][ch] + c1[ch], 0.0f);
    __syncthreads();

    // dec layer 2 (split-k)
    a = 0.f;
    for (int k = hf * 64; k < hf * 64 + 64; ++k)
        a = fmaf(tb[k], D2[(k << 7) + ch], a);
    red[hf][ch] = a;
    __syncthreads();
    if (hf == 0)
        hb[ch] = fmaxf(red[0][ch] + red[1][ch] + c2[ch], 0.0f);
    __syncthreads();

    // dec layer 3: out[b] = dot(hb, D3) + c3
    if (hf == 0) red[0][ch] = hb[ch] * D3[ch];
    __syncthreads();
    if (t < 64) {
        float r = red[0][t] + red[0][t + 64];
#pragma unroll
        for (int s2 = 1; s2 < 64; s2 <<= 1)
            r += __shfl_xor(r, s2, 64);
        if (t == 0) out[b] = r + c3[0];
    }
}

extern "C" void kernel_launch(void* const* d_in, const int* in_sizes, int n_in,
                              void* d_out, int out_size, void* d_ws, size_t ws_size,
                              hipStream_t stream)
{
    (void)in_sizes; (void)n_in; (void)out_size; (void)ws_size;

    const int*   xcat  = (const int*)  d_in[0];
    const float* xfeat = (const float*)d_in[1];
    const float* emb   = (const float*)d_in[2];
    const float* W1    = (const float*)d_in[3];
    const float* b1    = (const float*)d_in[4];
    const float* W2    = (const float*)d_in[5];
    const float* b2    = (const float*)d_in[6];
    const float* W3    = (const float*)d_in[7];
    const float* b3    = (const float*)d_in[8];
    const float* D1    = (const float*)d_in[9];
    const float* c1    = (const float*)d_in[10];
    const float* D2    = (const float*)d_in[11];
    const float* c2    = (const float*)d_in[12];
    const float* D3    = (const float*)d_in[13];
    const float* c3    = (const float*)d_in[14];
    float* out = (float*)d_out;

    float* x       = (float*)d_ws;                 // 65536 f
    short* pw1     = (short*)(x + NB * NN * 64);   // 8192 s
    short* pw2     = pw1 + 8 * 2 * 64 * 8;         // 16384 s
    short* pw3     = pw2 + 8 * 4 * 64 * 8;         // 16384 s
    float* partial = (float*)(pw3 + 8 * 4 * 64 * 8); // 4*257*128 f = 526336 B

    prep_kernel<<<276, 256, 0, stream>>>(xcat, xfeat, emb, W1, W2, W3,
                                         x, pw1, pw2, pw3);
    pair_mlp<<<dim3(257, NB), 256, 0, stream>>>(x, pw1, b1, pw2, b2, pw3, b3, partial);
    reduce_decode<<<NB, 256, 0, stream>>>(partial, D1, c1, D2, c2, D3, c3, out);
}

// Round 4
// 129.532 us; speedup vs baseline: 2.5176x; 1.2039x over previous
//
#include <hip/hip_runtime.h>
#include <hip/hip_bf16.h>

// Eq2NetSet via bf16 MFMA (16x16x32, fp32 accum).
// Orientation: channels = M, pairs = N.  Per block: 128 triangle pairs.
//   L1: H1^T = W1^T (A) @ P^T (B),  K=64
//   L2: H2^T = W2^T @ H1^T,         K=128
//   L3: H3^T = W3^T @ H2^T,         K=128 -> relu -> weighted pair-sum
// Per-block partials -> two-stage tree reduction (R3's 4-block serial reducer
// was 52 us, latency-bound at 8 waves) -> decoder.

#define NB 4
#define NN 256
#define HD 128

typedef __attribute__((ext_vector_type(8))) short bf16x8;
typedef __attribute__((ext_vector_type(4))) short short4v;
typedef __attribute__((ext_vector_type(4))) float f32x4;

__device__ __forceinline__ short f2bf(float f) {
    // bf16 round-to-nearest-even (finite inputs)
    unsigned u = __builtin_bit_cast(unsigned, f);
    u = (u + 0x7fff + ((u >> 16) & 1)) >> 16;
    return (short)u;
}

__device__ __forceinline__ void tri_ij(int t, int& i, int& j) {
    j = (int)((sqrtf(8.0f * (float)t + 1.0f) - 1.0f) * 0.5f);
    while (((j + 1) * (j + 2) >> 1) <= t) ++j;
    while (((j * (j + 1)) >> 1) > t) --j;
    i = t - ((j * (j + 1)) >> 1);
}

// pack W[fanin][128] into A-fragment-linear bf16: packed[(mt*KQ+kq)*64 + lane][j],
// value = W[kq*32 + (lane>>4)*8 + j][mt*16 + (lane&15)]
__device__ __forceinline__ void pack_w(const float* __restrict__ W, short* __restrict__ pw,
                                       int KQ, int u) {
    int l  = u & 63;
    int kq = (u >> 6) % KQ;
    int mt = (u >> 6) / KQ;
    int q = l >> 4, m = l & 15;
    int c = mt * 16 + m;
#pragma unroll
    for (int j = 0; j < 8; ++j) {
        int k = kq * 32 + q * 8 + j;
        pw[u * 8 + j] = f2bf(W[k * 128 + c]);
    }
}

__global__ void prep_kernel(const int* __restrict__ xcat,
                            const float* __restrict__ xfeat,
                            const float* __restrict__ emb,
                            const float* __restrict__ W1,
                            const float* __restrict__ W2,
                            const float* __restrict__ W3,
                            float* __restrict__ x,
                            short* __restrict__ pw1,
                            short* __restrict__ pw2,
                            short* __restrict__ pw3)
{
    int bid = blockIdx.x;
    int tid = threadIdx.x;
    if (bid < 256) {                       // build x[4][256][64] fp32
        int f = bid * 256 + tid;
        int d = f & 63;
        int nn = f >> 6;                   // b*256+n
        float v;
        if (d < 63) v = emb[xcat[nn] * 63 + d];
        else        v = xfeat[nn];
        x[f] = v;
    } else if (bid < 260) {                // W1: 8mt*2kq*64 = 1024 threads
        pack_w(W1, pw1, 2, (bid - 256) * 256 + tid);
    } else if (bid < 268) {                // W2: 8mt*4kq*64 = 2048
        pack_w(W2, pw2, 4, (bid - 260) * 256 + tid);
    } else {                               // W3
        pack_w(W3, pw3, 4, (bid - 268) * 256 + tid);
    }
}

__global__ __launch_bounds__(256, 3) void pair_mlp(
    const float* __restrict__ x,
    const short* __restrict__ pw1, const float* __restrict__ b1,
    const short* __restrict__ pw2, const float* __restrict__ b2,
    const short* __restrict__ pw3, const float* __restrict__ b3,
    float* __restrict__ partialOut)
{
    __shared__ short smP[128 * 64];    // 16 KB  P^T tile, row=pair, 64 bf16 (8 chunks)
    __shared__ short smH[128 * 128];   // 32 KB  H tile,   row=pair, 128 bf16 (16 chunks)
    __shared__ float smW[128];         // pair weights (1 diag / 2 off-diag)

    const int tid = threadIdx.x;
    const int l = tid & 63;
    const int w = __builtin_amdgcn_readfirstlane(tid >> 6);  // wave 0..3
    const int wm = w >> 1;             // channel half: mt in [wm*4, wm*4+4)
    const int wn = w & 1;              // pair half:    pairs [wn*64, wn*64+64)
    const int q = l >> 4;
    const int m = l & 15;
    const int b = blockIdx.y;
    const int tbase = blockIdx.x * 128;          // triangle index base for this tile
    const float* xb = x + (b << 14);
    char* smPc = (char*)smP;
    char* smHc = (char*)smH;

    // ---- build P^T tile: 256 threads, thread = (pair p = tid>>1, half = tid&1) ----
    {
        const int p = tid >> 1;
        const int half = tid & 1;
        int i, j;
        tri_ij(tbase + p, i, j);
        if (half == 0) smW[p] = (i == j) ? 1.0f : 2.0f;
        const float4* xi4 = (const float4*)(xb + (i << 6) + half * 32);
        const float4* xj4 = (const float4*)(xb + (j << 6) + half * 32);
#pragma unroll
        for (int c = 0; c < 4; ++c) {
            float4 a0 = xi4[2 * c], a1 = xi4[2 * c + 1];
            float4 u0 = xj4[2 * c], u1 = xj4[2 * c + 1];
            bf16x8 s;
            s[0] = f2bf(a0.x * u0.x); s[1] = f2bf(a0.y * u0.y);
            s[2] = f2bf(a0.z * u0.z); s[3] = f2bf(a0.w * u0.w);
            s[4] = f2bf(a1.x * u1.x); s[5] = f2bf(a1.y * u1.y);
            s[6] = f2bf(a1.z * u1.z); s[7] = f2bf(a1.w * u1.w);
            int chunk = half * 4 + c;
            int phys = chunk ^ (p & 7);
            *(bf16x8*)(smPc + p * 128 + phys * 16) = s;
        }
    }
    __syncthreads();

    f32x4 acc[4][4];
    const f32x4 zero = {0.f, 0.f, 0.f, 0.f};

    // ---- L1: K=64, B from smP ----
#pragma unroll
    for (int mt = 0; mt < 4; ++mt)
#pragma unroll
        for (int nt = 0; nt < 4; ++nt) acc[mt][nt] = zero;

#pragma unroll
    for (int kq = 0; kq < 2; ++kq) {
        bf16x8 bfr[4], afr[4];
#pragma unroll
        for (int nt = 0; nt < 4; ++nt) {
            int pair = wn * 64 + nt * 16 + m;
            int phys = (kq * 4 + q) ^ (pair & 7);
            bfr[nt] = *(const bf16x8*)(smPc + pair * 128 + phys * 16);
        }
#pragma unroll
        for (int mt = 0; mt < 4; ++mt)
            afr[mt] = *(const bf16x8*)(pw1 + ((((wm * 4 + mt) * 2 + kq) * 64 + l) << 3));
#pragma unroll
        for (int mt = 0; mt < 4; ++mt)
#pragma unroll
            for (int nt = 0; nt < 4; ++nt)
                acc[mt][nt] = __builtin_amdgcn_mfma_f32_16x16x32_bf16(afr[mt], bfr[nt], acc[mt][nt], 0, 0, 0);
    }

    // epilogue L1 -> smH (bias + relu + bf16), swizzled ds_write_b64
#pragma unroll
    for (int mt = 0; mt < 4; ++mt) {
        int mtg = wm * 4 + mt;
        float4 bv = *(const float4*)(b1 + mtg * 16 + q * 4);
#pragma unroll
        for (int nt = 0; nt < 4; ++nt) {
            int pair = wn * 64 + nt * 16 + m;
            short4v sv;
            sv[0] = f2bf(fmaxf(acc[mt][nt][0] + bv.x, 0.f));
            sv[1] = f2bf(fmaxf(acc[mt][nt][1] + bv.y, 0.f));
            sv[2] = f2bf(fmaxf(acc[mt][nt][2] + bv.z, 0.f));
            sv[3] = f2bf(fmaxf(acc[mt][nt][3] + bv.w, 0.f));
            int chunk = mtg * 2 + (q >> 1);
            int phys = chunk ^ (pair & 15);
            *(short4v*)(smHc + pair * 256 + phys * 16 + (q & 1) * 8) = sv;
        }
    }
    __syncthreads();

    // ---- L2: K=128, B from smH (H1) ----
#pragma unroll
    for (int mt = 0; mt < 4; ++mt)
#pragma unroll
        for (int nt = 0; nt < 4; ++nt) acc[mt][nt] = zero;

#pragma unroll
    for (int kq = 0; kq < 4; ++kq) {
        bf16x8 bfr[4], afr[4];
#pragma unroll
        for (int nt = 0; nt < 4; ++nt) {
            int pair = wn * 64 + nt * 16 + m;
            int phys = (kq * 4 + q) ^ (pair & 15);
            bfr[nt] = *(const bf16x8*)(smHc + pair * 256 + phys * 16);
        }
#pragma unroll
        for (int mt = 0; mt < 4; ++mt)
            afr[mt] = *(const bf16x8*)(pw2 + ((((wm * 4 + mt) * 4 + kq) * 64 + l) << 3));
#pragma unroll
        for (int mt = 0; mt < 4; ++mt)
#pragma unroll
            for (int nt = 0; nt < 4; ++nt)
                acc[mt][nt] = __builtin_amdgcn_mfma_f32_16x16x32_bf16(afr[mt], bfr[nt], acc[mt][nt], 0, 0, 0);
    }
    __syncthreads();   // all reads of H1 done before overwriting smH

    // epilogue L2 -> smH (H2)
#pragma unroll
    for (int mt = 0; mt < 4; ++mt) {
        int mtg = wm * 4 + mt;
        float4 bv = *(const float4*)(b2 + mtg * 16 + q * 4);
#pragma unroll
        for (int nt = 0; nt < 4; ++nt) {
            int pair = wn * 64 + nt * 16 + m;
            short4v sv;
            sv[0] = f2bf(fmaxf(acc[mt][nt][0] + bv.x, 0.f));
            sv[1] = f2bf(fmaxf(acc[mt][nt][1] + bv.y, 0.f));
            sv[2] = f2bf(fmaxf(acc[mt][nt][2] + bv.z, 0.f));
            sv[3] = f2bf(fmaxf(acc[mt][nt][3] + bv.w, 0.f));
            int chunk = mtg * 2 + (q >> 1);
            int phys = chunk ^ (pair & 15);
            *(short4v*)(smHc + pair * 256 + phys * 16 + (q & 1) * 8) = sv;
        }
    }
    __syncthreads();

    // ---- L3: K=128, B from smH (H2) ----
#pragma unroll
    for (int mt = 0; mt < 4; ++mt)
#pragma unroll
        for (int nt = 0; nt < 4; ++nt) acc[mt][nt] = zero;

#pragma unroll
    for (int kq = 0; kq < 4; ++kq) {
        bf16x8 bfr[4], afr[4];
#pragma unroll
        for (int nt = 0; nt < 4; ++nt) {
            int pair = wn * 64 + nt * 16 + m;
            int phys = (kq * 4 + q) ^ (pair & 15);
            bfr[nt] = *(const bf16x8*)(smHc + pair * 256 + phys * 16);
        }
#pragma unroll
        for (int mt = 0; mt < 4; ++mt)
            afr[mt] = *(const bf16x8*)(pw3 + ((((wm * 4 + mt) * 4 + kq) * 64 + l) << 3));
#pragma unroll
        for (int mt = 0; mt < 4; ++mt)
#pragma unroll
            for (int nt = 0; nt < 4; ++nt)
                acc[mt][nt] = __builtin_amdgcn_mfma_f32_16x16x32_bf16(afr[mt], bfr[nt], acc[mt][nt], 0, 0, 0);
    }

    // ---- reduction: relu(h3 + b3) * pair-weight, sum over pairs -> LDS -> ws ----
    float wpv[4];
#pragma unroll
    for (int nt = 0; nt < 4; ++nt)
        wpv[nt] = smW[wn * 64 + nt * 16 + m];

    float* smPart = (float*)smP;   // 256 floats; smP dead since L1
#pragma unroll
    for (int mt = 0; mt < 4; ++mt) {
        int mtg = wm * 4 + mt;
        float4 bv = *(const float4*)(b3 + mtg * 16 + q * 4);
        float vs0 = 0.f, vs1 = 0.f, vs2 = 0.f, vs3 = 0.f;
#pragma unroll
        for (int nt = 0; nt < 4; ++nt) {
            vs0 += wpv[nt] * fmaxf(acc[mt][nt][0] + bv.x, 0.f);
            vs1 += wpv[nt] * fmaxf(acc[mt][nt][1] + bv.y, 0.f);
            vs2 += wpv[nt] * fmaxf(acc[mt][nt][2] + bv.z, 0.f);
            vs3 += wpv[nt] * fmaxf(acc[mt][nt][3] + bv.w, 0.f);
        }
#pragma unroll
        for (int s = 1; s < 16; s <<= 1) {
            vs0 += __shfl_xor(vs0, s, 64);
            vs1 += __shfl_xor(vs1, s, 64);
            vs2 += __shfl_xor(vs2, s, 64);
            vs3 += __shfl_xor(vs3, s, 64);
        }
        if (m == 0) {
            float* p = smPart + wn * HD + mtg * 16 + q * 4;
            p[0] = vs0; p[1] = vs1; p[2] = vs2; p[3] = vs3;
        }
    }
    __syncthreads();

    if (tid < HD) {
        float v = smPart[tid] + smPart[HD + tid];
        partialOut[(b * 257 + blockIdx.x) * HD + tid] = v;   // coalesced 512B/block
    }
}

// stage-1 tree reduce: block (g,b) sums tiles [16g, 16g+16) -> partial2[b][17][128]
__global__ __launch_bounds__(128) void reduce1(const float* __restrict__ partial,
                                               float* __restrict__ partial2)
{
    const int ch = threadIdx.x;          // 128 threads
    const int g = blockIdx.x;            // 0..16
    const int b = blockIdx.y;
    const float* base = partial + (b * 257 + g * 16) * HD + ch;
    float s = 0.f;
#pragma unroll
    for (int t = 0; t < 16; ++t) {
        int tl = g * 16 + t;
        s += (tl < 257) ? base[t * HD] : 0.f;
    }
    partial2[(b * 17 + g) * HD + ch] = s;
}

__global__ void reduce_decode(const float* __restrict__ partial2,
                              const float* __restrict__ D1, const float* __restrict__ c1,
                              const float* __restrict__ D2, const float* __restrict__ c2,
                              const float* __restrict__ D3, const float* __restrict__ c3,
                              float* __restrict__ out)
{
    __shared__ float red[2][HD];
    __shared__ float hb[HD];
    __shared__ float tb[HD];
    const int b = blockIdx.x;
    const int t = threadIdx.x;          // 256 threads
    const int ch = t & 127, hf = t >> 7;

    // sum 17 stage-1 partials per channel (split over 2 halves, unrolled)
    float s = 0.f;
#pragma unroll
    for (int g = 0; g < 9; ++g) {
        int tl = hf * 9 + g;
        s += (tl < 17) ? partial2[(b * 17 + tl) * HD + ch] : 0.f;
    }
    red[hf][ch] = s;
    __syncthreads();
    if (hf == 0)
        hb[ch] = fmaxf((red[0][ch] + red[1][ch]) * (1.0f / 65536.0f), 0.0f);
    __syncthreads();

    // dec layer 1 (split-k)
    float a = 0.f;
    for (int k = hf * 64; k < hf * 64 + 64; ++k)
        a = fmaf(hb[k], D1[(k << 7) + ch], a);
    red[hf][ch] = a;
    __syncthreads();
    if (hf == 0)
        tb[ch] = fmaxf(red[0][ch] + red[1][ch] + c1[ch], 0.0f);
    __syncthreads();

    // dec layer 2 (split-k)
    a = 0.f;
    for (int k = hf * 64; k < hf * 64 + 64; ++k)
        a = fmaf(tb[k], D2[(k << 7) + ch], a);
    red[hf][ch] = a;
    __syncthreads();
    if (hf == 0)
        hb[ch] = fmaxf(red[0][ch] + red[1][ch] + c2[ch], 0.0f);
    __syncthreads();

    // dec layer 3: out[b] = dot(hb, D3) + c3
    if (hf == 0) red[0][ch] = hb[ch] * D3[ch];
    __syncthreads();
    if (t < 64) {
        float r = red[0][t] + red[0][t + 64];
#pragma unroll
        for (int s2 = 1; s2 < 64; s2 <<= 1)
            r += __shfl_xor(r, s2, 64);
        if (t == 0) out[b] = r + c3[0];
    }
}

extern "C" void kernel_launch(void* const* d_in, const int* in_sizes, int n_in,
                              void* d_out, int out_size, void* d_ws, size_t ws_size,
                              hipStream_t stream)
{
    (void)in_sizes; (void)n_in; (void)out_size; (void)ws_size;

    const int*   xcat  = (const int*)  d_in[0];
    const float* xfeat = (const float*)d_in[1];
    const float* emb   = (const float*)d_in[2];
    const float* W1    = (const float*)d_in[3];
    const float* b1    = (const float*)d_in[4];
    const float* W2    = (const float*)d_in[5];
    const float* b2    = (const float*)d_in[6];
    const float* W3    = (const float*)d_in[7];
    const float* b3    = (const float*)d_in[8];
    const float* D1    = (const float*)d_in[9];
    const float* c1    = (const float*)d_in[10];
    const float* D2    = (const float*)d_in[11];
    const float* c2    = (const float*)d_in[12];
    const float* D3    = (const float*)d_in[13];
    const float* c3    = (const float*)d_in[14];
    float* out = (float*)d_out;

    float* x        = (float*)d_ws;                    // 65536 f
    short* pw1      = (short*)(x + NB * NN * 64);      // 8192 s
    short* pw2      = pw1 + 8 * 2 * 64 * 8;            // 16384 s
    short* pw3      = pw2 + 8 * 4 * 64 * 8;            // 16384 s
    float* partial  = (float*)(pw3 + 8 * 4 * 64 * 8);  // 4*257*128 f
    float* partial2 = partial + NB * 257 * HD;         // 4*17*128 f

    prep_kernel<<<276, 256, 0, stream>>>(xcat, xfeat, emb, W1, W2, W3,
                                         x, pw1, pw2, pw3);
    pair_mlp<<<dim3(257, NB), 256, 0, stream>>>(x, pw1, b1, pw2, b2, pw3, b3, partial);
    reduce1<<<dim3(17, NB), 128, 0, stream>>>(partial, partial2);
    reduce_decode<<<NB, 256, 0, stream>>>(partial2, D1, c1, D2, c2, D3, c3, out);
}